// Round 2
// baseline (347.799 us; speedup 1.0000x reference)
//
#include <hip/hip_runtime.h>
#include <hip/hip_bf16.h>
#include <stdint.h>
#include <stddef.h>

#define DEV static __device__ __forceinline__

typedef __attribute__((ext_vector_type(8))) short short8;   // 8 bf16 (4 VGPRs) MFMA A/B frag
typedef __attribute__((ext_vector_type(4))) float floatx4;  // MFMA C/D frag

constexpr int Tn = 4096, Dn = 512;
constexpr int NC = 128, CTm = 32;   // scan: 128 chunks of 32 along T

union U8s { uint4 u4; unsigned short us[8]; };
union U4f { float4 f4; float f[4]; };
union U4s { uint2 u2; unsigned short us[4]; };

DEV float b2f(unsigned short u) {
  union { unsigned int i; float f; } c; c.i = ((unsigned int)u) << 16; return c.f;
}
DEV unsigned short f2b(float f) {  // RNE float->bf16
  union { float f; unsigned int u; } c; c.f = f;
  unsigned int r = c.u + 0x7fffu + ((c.u >> 16) & 1u);
  return (unsigned short)(r >> 16);
}
DEV float fast_tanh(float x) {     // robust at +/-inf: 1-2/(e^{2x}+1)
  float e = __expf(2.0f * x);
  return 1.0f - 2.0f / (e + 1.0f);
}

// ---------------- scan pass 1: per-chunk partial sums (fp32) ----------------
__global__ void k_scan_partial(const float* __restrict__ dec, float* __restrict__ part) {
  int idx = blockIdx.x * 256 + threadIdx.x;   // B*NC*(D/4) = 131072 threads
  int d4 = idx & 127;
  int c  = (idx >> 7) & (NC - 1);
  int b  = idx >> 14;
  const float* p = dec + ((size_t)b * Tn + (size_t)c * CTm) * Dn + d4 * 4;
  float s[4] = {0,0,0,0};
#pragma unroll 4
  for (int i = 0; i < CTm; ++i) {
    U4f v; v.f4 = *(const float4*)(p + (size_t)i * Dn);
#pragma unroll
    for (int j = 0; j < 4; ++j) s[j] += v.f[j];
  }
  float* o = part + ((size_t)(b * NC + c)) * Dn + d4 * 4;
#pragma unroll
  for (int j = 0; j < 4; ++j) o[j] = s[j];
}

// ---------------- scan pass 2: exclusive prefix over chunks, in place -------
__global__ void k_scan_prefix(float* __restrict__ part) {
  int idx = blockIdx.x * 256 + threadIdx.x;   // B*D = 4096 threads
  int d = idx & 511; int b = idx >> 9;
  float* p = part + (size_t)b * NC * Dn + d;
  float run = 0.f;
#pragma unroll 4
  for (int c = 0; c < NC; ++c) {
    float v = p[(size_t)c * Dn];
    p[(size_t)c * Dn] = run;
    run += v;
  }
}

// ---------------- scan pass 3: running mean -> bf16 M -----------------------
__global__ void k_scan_apply(const float* __restrict__ dec,
                             const float* __restrict__ part,
                             unsigned short* __restrict__ M) {
  int idx = blockIdx.x * 256 + threadIdx.x;   // 131072 threads
  int d4 = idx & 127;
  int c  = (idx >> 7) & (NC - 1);
  int b  = idx >> 14;
  size_t rbase = (size_t)b * Tn + (size_t)c * CTm;
  const float* pp = part + ((size_t)(b * NC + c)) * Dn + d4 * 4;
  float s[4];
#pragma unroll
  for (int j = 0; j < 4; ++j) s[j] = pp[j];
  int t0 = c * CTm;
  for (int i = 0; i < CTm; ++i) {
    U4f v; v.f4 = *(const float4*)(dec + (rbase + i) * Dn + d4 * 4);
    U4s o;
    float inv = 1.0f / (float)(t0 + i + 1);
#pragma unroll
    for (int j = 0; j < 4; ++j) { s[j] += v.f[j]; o.us[j] = f2b(s[j] * inv); }
    *(uint2*)(M + (rbase + i) * Dn + d4 * 4) = o.u2;
  }
}

// ---------------- sp = summ @ W1 (fp32, tiny) -------------------------------
__global__ void k_sproj(const float* __restrict__ summ,
                        const float* __restrict__ W1,
                        float* __restrict__ sp) {
  int idx = blockIdx.x * 256 + threadIdx.x;   // B*D = 4096
  int j = idx & 511; int b = idx >> 9;
  const float* s = summ + b * Dn;
  float acc = 0.f;
#pragma unroll 4
  for (int k = 0; k < Dn; ++k) acc += s[k] * W1[(size_t)k * Dn + j];
  sp[b * Dn + j] = acc;
}

// ---------------- spo = sp @ W_out + b_out (fp32, tiny) ---------------------
__global__ void k_sproj2(const float* __restrict__ sp,
                         const float* __restrict__ Wo,
                         const float* __restrict__ bo,
                         float* __restrict__ spo) {
  int idx = blockIdx.x * 256 + threadIdx.x;   // B*D = 4096
  int n = idx & 511; int b = idx >> 9;
  const float* s = sp + b * Dn;
  float acc = bo[n];
#pragma unroll 4
  for (int j = 0; j < Dn; ++j) acc += s[j] * Wo[(size_t)j * Dn + n];
  spo[b * Dn + n] = acc;
}

// ------------- 512x512 fp32->bf16 transpose (out[n][k] = in[k][n]) ----------
__global__ void k_transpose512(const float* __restrict__ in,
                               unsigned short* __restrict__ out) {
  __shared__ float t[64][65];
  int bx = blockIdx.x & 7, by = blockIdx.x >> 3;
  int n0 = bx * 64, k0 = by * 64;
#pragma unroll
  for (int l = 0; l < 16; ++l) {
    int lin = l * 256 + threadIdx.x;
    int r = lin >> 6, c = lin & 63;
    t[r][c] = in[(size_t)(k0 + r) * 512 + n0 + c];
  }
  __syncthreads();
#pragma unroll
  for (int l = 0; l < 16; ++l) {
    int lin = l * 256 + threadIdx.x;
    int r = lin >> 6, c = lin & 63;
    out[(size_t)(n0 + r) * 512 + k0 + c] = f2b(t[c][r]);
  }
}

// ---------------- 512x512 fp32 -> bf16 elementwise copy ---------------------
__global__ void k_convert512(const float* __restrict__ in, unsigned short* __restrict__ out) {
  int idx = blockIdx.x * 256 + threadIdx.x;   // 65536 threads, 4 elems each
  U4f v; v.f4 = *(const float4*)(in + (size_t)idx * 4);
  U4s o;
#pragma unroll
  for (int j = 0; j < 4; ++j) o.us[j] = f2b(v.f[j]);
  *(uint2*)(out + (size_t)idx * 4) = o.u2;
}

// ---------------- MFMA GEMM: C[m][n] = epi(sum_k A[m][k]*BT[n][k]) ----------
// A, BT, C: bf16. EPI 0: tanh(acc + bias[n]) ; EPI 2: acc ;
// EPI 3: tanh(sproj[b][n] - acc)  (b = rowg >> 12)
template<int EPI>
__global__ __launch_bounds__(256, 2)
void k_gemm(const unsigned short* __restrict__ A, const unsigned short* __restrict__ BT,
            unsigned short* __restrict__ C, const float* __restrict__ bias,
            const float* __restrict__ sproj) {
  __shared__ alignas(16) unsigned short sA[128 * 64];
  __shared__ alignas(16) unsigned short sB[128 * 64];
  const int tid  = threadIdx.x;
  const int lane = tid & 63;
  const int w    = tid >> 6;
  const int m0   = blockIdx.x * 128;
  const int n0   = blockIdx.y * 128;
  const int wm   = (w >> 1) * 64;
  const int wn   = (w & 1) * 64;
  const int rs   = lane & 15;
  const int quad = lane >> 4;

  floatx4 acc[4][4];
#pragma unroll
  for (int i = 0; i < 4; ++i)
#pragma unroll
    for (int j = 0; j < 4; ++j) acc[i][j] = (floatx4){0.f, 0.f, 0.f, 0.f};

  for (int kt = 0; kt < 512; kt += 64) {
    // stage A[128x64], BT[128x64] tiles -> LDS (synchronous uint4 loads this round)
#pragma unroll
    for (int l = 0; l < 4; ++l) {
      int ch = l * 256 + tid;
      int r = ch >> 3, kc = ch & 7;
      *(uint4*)(sA + (size_t)ch * 8) = *(const uint4*)(A  + (size_t)(m0 + r) * 512 + kt + kc * 8);
      *(uint4*)(sB + (size_t)ch * 8) = *(const uint4*)(BT + (size_t)(n0 + r) * 512 + kt + kc * 8);
    }
    __syncthreads();

#pragma unroll
    for (int kk = 0; kk < 2; ++kk) {
      const int kb = kk * 32 + quad * 8;   // A-frag layout: A[m=rs][k=quad*8+j]
      short8 af[4], bfr[4];
#pragma unroll
      for (int i = 0; i < 4; ++i)
        af[i] = *(const short8*)(sA + (size_t)(wm + i * 16 + rs) * 64 + kb);
#pragma unroll
      for (int j = 0; j < 4; ++j)
        bfr[j] = *(const short8*)(sB + (size_t)(wn + j * 16 + rs) * 64 + kb);
#pragma unroll
      for (int i = 0; i < 4; ++i)
#pragma unroll
        for (int j = 0; j < 4; ++j)
          acc[i][j] = __builtin_amdgcn_mfma_f32_16x16x32_bf16(af[i], bfr[j], acc[i][j], 0, 0, 0);
    }
    __syncthreads();
  }

  // C/D layout: col = lane&15, row = quad*4 + reg
#pragma unroll
  for (int i = 0; i < 4; ++i) {
#pragma unroll
    for (int j = 0; j < 4; ++j) {
      const int colg = n0 + wn + j * 16 + rs;
#pragma unroll
      for (int r = 0; r < 4; ++r) {
        const int rowg = m0 + wm + i * 16 + quad * 4 + r;
        float v = acc[i][j][r];
        if constexpr (EPI == 0)      v = fast_tanh(v + bias[colg]);
        else if constexpr (EPI == 3) v = fast_tanh(sproj[(rowg >> 12) * Dn + colg] - v);
        C[(size_t)rowg * 512 + colg] = f2b(v);
      }
    }
  }
}

// ---------------- residual + LayerNorm (wave per row), fp32 out -------------
__global__ void k_ln(const unsigned short* __restrict__ F, const float* __restrict__ dec,
                     const float* __restrict__ gamma, const float* __restrict__ beta,
                     float* __restrict__ out) {
  int row  = blockIdx.x * 4 + (threadIdx.x >> 6);
  int lane = threadIdx.x & 63;
  size_t base = (size_t)row * Dn + lane * 8;
  U8s f8; f8.u4 = *(const uint4*)(F + base);
  U4f d0, d1; d0.f4 = *(const float4*)(dec + base); d1.f4 = *(const float4*)(dec + base + 4);
  float x[8]; float s = 0.f, sq = 0.f;
#pragma unroll
  for (int j = 0; j < 8; ++j) {
    float dv = (j < 4) ? d0.f[j] : d1.f[j - 4];
    x[j] = b2f(f8.us[j]) + dv; s += x[j]; sq += x[j] * x[j];
  }
#pragma unroll
  for (int o = 32; o > 0; o >>= 1) { s += __shfl_xor(s, o, 64); sq += __shfl_xor(sq, o, 64); }
  float mu   = s * (1.0f / 512.0f);
  float var  = sq * (1.0f / 512.0f) - mu * mu;
  float rstd = rsqrtf(var + 1e-6f);
  U4f g0, g1, b0, b1, o0, o1;
  g0.f4 = *(const float4*)(gamma + lane * 8); g1.f4 = *(const float4*)(gamma + lane * 8 + 4);
  b0.f4 = *(const float4*)(beta  + lane * 8); b1.f4 = *(const float4*)(beta  + lane * 8 + 4);
#pragma unroll
  for (int j = 0; j < 8; ++j) {
    float g = (j < 4) ? g0.f[j] : g1.f[j - 4];
    float b = (j < 4) ? b0.f[j] : b1.f[j - 4];
    float v = (x[j] - mu) * rstd * g + b;
    if (j < 4) o0.f[j] = v; else o1.f[j - 4] = v;
  }
  *(float4*)(out + base) = o0.f4;
  *(float4*)(out + base + 4) = o1.f4;
}

extern "C" void kernel_launch(void* const* d_in, const int* in_sizes, int n_in,
                              void* d_out, int out_size, void* d_ws, size_t ws_size,
                              hipStream_t stream) {
  (void)in_sizes; (void)n_in; (void)out_size; (void)ws_size;
  const float* summ = (const float*)d_in[0];
  const float* dec  = (const float*)d_in[1];
  const float* Wh   = (const float*)d_in[2];
  const float* bh   = (const float*)d_in[3];
  const float* W1   = (const float*)d_in[4];
  const float* W2   = (const float*)d_in[5];
  const float* Wo   = (const float*)d_in[6];
  const float* bo   = (const float*)d_in[7];
  const float* gam  = (const float*)d_in[8];
  const float* bet  = (const float*)d_in[9];
  float* out = (float*)d_out;

  char* ws = (char*)d_ws;
  unsigned short* Mbuf  = (unsigned short*)(ws);                 // 32 MB bf16 M; later F
  unsigned short* Hbuf  = (unsigned short*)(ws + 33554432);      // 32 MB bf16 H
  float*          part  = (float*)(ws + 67108864);               // 2 MB fp32 partial sums
  float*          sp    = (float*)(ws + 69206016);               // 16 KB
  float*          spo   = (float*)(ws + 69222400);               // 16 KB
  unsigned short* WhT   = (unsigned short*)(ws + 69238784);      // 512 KB bf16
  unsigned short* WoT   = (unsigned short*)(ws + 69763072);      // 512 KB bf16
  unsigned short* W2b   = (unsigned short*)(ws + 70287360);      // 512 KB bf16 (W2 row-major)
  unsigned short* W2WoT = (unsigned short*)(ws + 70811648);      // 512 KB bf16 (= (W2@Wo)^T)

  // weight prep (fp32 -> bf16)
  k_transpose512<<<64, 256, 0, stream>>>(Wh, WhT);
  k_transpose512<<<64, 256, 0, stream>>>(Wo, WoT);
  k_convert512<<<256, 256, 0, stream>>>(W2, W2b);
  // (W2@Wo)^T = Wo^T @ W2^T : A = WoT (row-major), BT = W2b (row-major)
  k_gemm<2><<<dim3(4, 4), 256, 0, stream>>>(WoT, W2b, W2WoT, nullptr, nullptr);

  // causal running mean -> M (bf16)
  k_scan_partial<<<512, 256, 0, stream>>>(dec, part);
  k_scan_prefix<<<16, 256, 0, stream>>>(part);
  k_scan_apply<<<512, 256, 0, stream>>>(dec, part, Mbuf);

  // summarization path: spo = (summ@W1)@Wo + bo  (fp32 exact)
  k_sproj<<<16, 256, 0, stream>>>(summ, W1, sp);
  k_sproj2<<<16, 256, 0, stream>>>(sp, Wo, bo, spo);

  // H = tanh(M @ Wh + bh)
  k_gemm<0><<<dim3(256, 4), 256, 0, stream>>>(Mbuf, WhT, Hbuf, bh, nullptr);
  // F = tanh(spo[b] - H @ (W2@Wo))   (into Mbuf; M is dead)
  k_gemm<3><<<dim3(256, 4), 256, 0, stream>>>(Hbuf, W2WoT, Mbuf, nullptr, spo);

  // out = LayerNorm(F + dec) * gamma + beta
  k_ln<<<8192, 256, 0, stream>>>(Mbuf, dec, gam, bet, out);
}

// Round 3
// 276.571 us; speedup vs baseline: 1.2575x; 1.2575x over previous
//
#include <hip/hip_runtime.h>
#include <hip/hip_bf16.h>
#include <stdint.h>
#include <stddef.h>

#define DEV static __device__ __forceinline__

typedef __attribute__((ext_vector_type(8))) short short8;   // 8 bf16 (4 VGPRs) MFMA A/B frag
typedef __attribute__((ext_vector_type(4))) float floatx4;  // MFMA C/D frag

constexpr int Tn = 4096, Dn = 512;
constexpr int NC = 128, CTm = 32;   // scan: 128 chunks of 32 along T

union U8s { uint4 u4; unsigned short us[8]; };
union U4f { float4 f4; float f[4]; };
union U4s { uint2 u2; unsigned short us[4]; };

DEV float b2f(unsigned short u) {
  union { unsigned int i; float f; } c; c.i = ((unsigned int)u) << 16; return c.f;
}
DEV unsigned short f2b(float f) {  // RNE float->bf16
  union { float f; unsigned int u; } c; c.f = f;
  unsigned int r = c.u + 0x7fffu + ((c.u >> 16) & 1u);
  return (unsigned short)(r >> 16);
}
DEV float fast_tanh(float x) {     // robust at +/-inf: 1-2/(e^{2x}+1)
  float e = __expf(2.0f * x);
  return 1.0f - 2.0f / (e + 1.0f);
}

typedef __attribute__((address_space(1))) void GVOID;
typedef __attribute__((address_space(3))) void LVOID;
DEV void async16(const unsigned short* g, unsigned short* l) {
  __builtin_amdgcn_global_load_lds((GVOID*)g, (LVOID*)l, 16, 0, 0);
}

// ---------------- scan pass 1: per-chunk partial sums (fp32) ----------------
__global__ void k_scan_partial(const float* __restrict__ dec, float* __restrict__ part) {
  int idx = blockIdx.x * 256 + threadIdx.x;   // B*NC*(D/4) = 131072 threads
  int d4 = idx & 127;
  int c  = (idx >> 7) & (NC - 1);
  int b  = idx >> 14;
  const float* p = dec + ((size_t)b * Tn + (size_t)c * CTm) * Dn + d4 * 4;
  float s[4] = {0,0,0,0};
#pragma unroll 4
  for (int i = 0; i < CTm; ++i) {
    U4f v; v.f4 = *(const float4*)(p + (size_t)i * Dn);
#pragma unroll
    for (int j = 0; j < 4; ++j) s[j] += v.f[j];
  }
  float* o = part + ((size_t)(b * NC + c)) * Dn + d4 * 4;
#pragma unroll
  for (int j = 0; j < 4; ++j) o[j] = s[j];
}

// ---------------- scan pass 2: exclusive prefix over chunks, in place -------
__global__ void k_scan_prefix(float* __restrict__ part) {
  int idx = blockIdx.x * 256 + threadIdx.x;   // B*D = 4096 threads
  int d = idx & 511; int b = idx >> 9;
  float* p = part + (size_t)b * NC * Dn + d;
  float run = 0.f;
#pragma unroll 4
  for (int c = 0; c < NC; ++c) {
    float v = p[(size_t)c * Dn];
    p[(size_t)c * Dn] = run;
    run += v;
  }
}

// ---------------- scan pass 3: running mean -> bf16 M -----------------------
__global__ void k_scan_apply(const float* __restrict__ dec,
                             const float* __restrict__ part,
                             unsigned short* __restrict__ M) {
  int idx = blockIdx.x * 256 + threadIdx.x;   // 131072 threads
  int d4 = idx & 127;
  int c  = (idx >> 7) & (NC - 1);
  int b  = idx >> 14;
  size_t rbase = (size_t)b * Tn + (size_t)c * CTm;
  const float* pp = part + ((size_t)(b * NC + c)) * Dn + d4 * 4;
  float s[4];
#pragma unroll
  for (int j = 0; j < 4; ++j) s[j] = pp[j];
  int t0 = c * CTm;
  for (int i = 0; i < CTm; ++i) {
    U4f v; v.f4 = *(const float4*)(dec + (rbase + i) * Dn + d4 * 4);
    U4s o;
    float inv = 1.0f / (float)(t0 + i + 1);
#pragma unroll
    for (int j = 0; j < 4; ++j) { s[j] += v.f[j]; o.us[j] = f2b(s[j] * inv); }
    *(uint2*)(M + (rbase + i) * Dn + d4 * 4) = o.u2;
  }
}

// ------- spo[b][n] = bo[n] + sum_j summ[b][j] * W1WoT[n][j]  (wave/output) --
__global__ void k_svec(const float* __restrict__ summ,
                       const unsigned short* __restrict__ W1WoT,
                       const float* __restrict__ bo,
                       float* __restrict__ spo) {
  int widx = blockIdx.x * 4 + (threadIdx.x >> 6);   // 4096 waves total
  int lane = threadIdx.x & 63;
  int n = widx & 511; int b = widx >> 9;
  U8s w8; w8.u4 = *(const uint4*)(W1WoT + (size_t)n * Dn + lane * 8);
  U4f s0, s1;
  s0.f4 = *(const float4*)(summ + (size_t)b * Dn + lane * 8);
  s1.f4 = *(const float4*)(summ + (size_t)b * Dn + lane * 8 + 4);
  float acc = 0.f;
#pragma unroll
  for (int j = 0; j < 4; ++j) acc += s0.f[j] * b2f(w8.us[j]);
#pragma unroll
  for (int j = 0; j < 4; ++j) acc += s1.f[j] * b2f(w8.us[j + 4]);
#pragma unroll
  for (int o = 32; o > 0; o >>= 1) acc += __shfl_xor(acc, o, 64);
  if (lane == 0) spo[(size_t)b * Dn + n] = acc + bo[n];
}

// ------------- 512x512 fp32->bf16 transpose (out[n][k] = in[k][n]) ----------
__global__ void k_transpose512(const float* __restrict__ in,
                               unsigned short* __restrict__ out) {
  __shared__ float t[64][65];
  int bx = blockIdx.x & 7, by = blockIdx.x >> 3;
  int n0 = bx * 64, k0 = by * 64;
#pragma unroll
  for (int l = 0; l < 16; ++l) {
    int lin = l * 256 + threadIdx.x;
    int r = lin >> 6, c = lin & 63;
    t[r][c] = in[(size_t)(k0 + r) * 512 + n0 + c];
  }
  __syncthreads();
#pragma unroll
  for (int l = 0; l < 16; ++l) {
    int lin = l * 256 + threadIdx.x;
    int r = lin >> 6, c = lin & 63;
    out[(size_t)(n0 + r) * 512 + k0 + c] = f2b(t[c][r]);
  }
}

// ---------------- 512x512 fp32 -> bf16 elementwise copy ---------------------
__global__ void k_convert512(const float* __restrict__ in, unsigned short* __restrict__ out) {
  int idx = blockIdx.x * 256 + threadIdx.x;   // 65536 threads, 4 elems each
  U4f v; v.f4 = *(const float4*)(in + (size_t)idx * 4);
  U4s o;
#pragma unroll
  for (int j = 0; j < 4; ++j) o.us[j] = f2b(v.f[j]);
  *(uint2*)(out + (size_t)idx * 4) = o.u2;
}

// ---------------- MFMA GEMM: C[m][n] = epi(sum_k A[m][k]*BT[n][k]) ----------
// A, BT, C: bf16. EPI 0: tanh(acc + bias[n]) ; EPI 2: acc ;
// EPI 3: tanh(sproj[b][n] - acc)  (b = rowg >> 12)
template<int EPI>
__global__ __launch_bounds__(256, 2)
void k_gemm(const unsigned short* __restrict__ A, const unsigned short* __restrict__ BT,
            unsigned short* __restrict__ C, const float* __restrict__ bias,
            const float* __restrict__ sproj) {
  __shared__ alignas(16) unsigned short sA[128 * 64];
  __shared__ alignas(16) unsigned short sB[128 * 64];
  const int tid  = threadIdx.x;
  const int lane = tid & 63;
  const int w    = tid >> 6;
  const int m0   = blockIdx.x * 128;
  const int n0   = blockIdx.y * 128;
  const int wm   = (w >> 1) * 64;
  const int wn   = (w & 1) * 64;
  const int rs   = lane & 15;
  const int quad = lane >> 4;

  floatx4 acc[4][4];
#pragma unroll
  for (int i = 0; i < 4; ++i)
#pragma unroll
    for (int j = 0; j < 4; ++j) acc[i][j] = (floatx4){0.f, 0.f, 0.f, 0.f};

  for (int kt = 0; kt < 512; kt += 64) {
    // stage A[128x64], BT[128x64] -> LDS via width-16 global_load_lds
    // (wave-uniform LDS base + lane*16: ch = l*256 + tid is contiguous per wave)
#pragma unroll
    for (int l = 0; l < 4; ++l) {
      int ch = l * 256 + tid;
      int r = ch >> 3, kc = ch & 7;
      async16(A  + (size_t)(m0 + r) * 512 + kt + kc * 8, sA + (size_t)ch * 8);
      async16(BT + (size_t)(n0 + r) * 512 + kt + kc * 8, sB + (size_t)ch * 8);
    }
    asm volatile("s_waitcnt vmcnt(0)" ::: "memory");
    __syncthreads();

#pragma unroll
    for (int kk = 0; kk < 2; ++kk) {
      const int kb = kk * 32 + quad * 8;   // A-frag layout: A[m=rs][k=quad*8+j]
      short8 af[4], bfr[4];
#pragma unroll
      for (int i = 0; i < 4; ++i)
        af[i] = *(const short8*)(sA + (size_t)(wm + i * 16 + rs) * 64 + kb);
#pragma unroll
      for (int j = 0; j < 4; ++j)
        bfr[j] = *(const short8*)(sB + (size_t)(wn + j * 16 + rs) * 64 + kb);
#pragma unroll
      for (int i = 0; i < 4; ++i)
#pragma unroll
        for (int j = 0; j < 4; ++j)
          acc[i][j] = __builtin_amdgcn_mfma_f32_16x16x32_bf16(af[i], bfr[j], acc[i][j], 0, 0, 0);
    }
    __syncthreads();
  }

  // C/D layout: col = lane&15, row = quad*4 + reg
#pragma unroll
  for (int i = 0; i < 4; ++i) {
#pragma unroll
    for (int j = 0; j < 4; ++j) {
      const int colg = n0 + wn + j * 16 + rs;
#pragma unroll
      for (int r = 0; r < 4; ++r) {
        const int rowg = m0 + wm + i * 16 + quad * 4 + r;
        float v = acc[i][j][r];
        if constexpr (EPI == 0)      v = fast_tanh(v + bias[colg]);
        else if constexpr (EPI == 3) v = fast_tanh(sproj[(rowg >> 12) * Dn + colg] - v);
        C[(size_t)rowg * 512 + colg] = f2b(v);
      }
    }
  }
}

// ---------------- residual + LayerNorm (wave per row), fp32 out -------------
__global__ void k_ln(const unsigned short* __restrict__ F, const float* __restrict__ dec,
                     const float* __restrict__ gamma, const float* __restrict__ beta,
                     float* __restrict__ out) {
  int row  = blockIdx.x * 4 + (threadIdx.x >> 6);
  int lane = threadIdx.x & 63;
  size_t base = (size_t)row * Dn + lane * 8;
  U8s f8; f8.u4 = *(const uint4*)(F + base);
  U4f d0, d1; d0.f4 = *(const float4*)(dec + base); d1.f4 = *(const float4*)(dec + base + 4);
  float x[8]; float s = 0.f, sq = 0.f;
#pragma unroll
  for (int j = 0; j < 8; ++j) {
    float dv = (j < 4) ? d0.f[j] : d1.f[j - 4];
    x[j] = b2f(f8.us[j]) + dv; s += x[j]; sq += x[j] * x[j];
  }
#pragma unroll
  for (int o = 32; o > 0; o >>= 1) { s += __shfl_xor(s, o, 64); sq += __shfl_xor(sq, o, 64); }
  float mu   = s * (1.0f / 512.0f);
  float var  = sq * (1.0f / 512.0f) - mu * mu;
  float rstd = rsqrtf(var + 1e-6f);
  U4f g0, g1, b0, b1, o0, o1;
  g0.f4 = *(const float4*)(gamma + lane * 8); g1.f4 = *(const float4*)(gamma + lane * 8 + 4);
  b0.f4 = *(const float4*)(beta  + lane * 8); b1.f4 = *(const float4*)(beta  + lane * 8 + 4);
#pragma unroll
  for (int j = 0; j < 8; ++j) {
    float g = (j < 4) ? g0.f[j] : g1.f[j - 4];
    float b = (j < 4) ? b0.f[j] : b1.f[j - 4];
    float v = (x[j] - mu) * rstd * g + b;
    if (j < 4) o0.f[j] = v; else o1.f[j - 4] = v;
  }
  *(float4*)(out + base) = o0.f4;
  *(float4*)(out + base + 4) = o1.f4;
}

extern "C" void kernel_launch(void* const* d_in, const int* in_sizes, int n_in,
                              void* d_out, int out_size, void* d_ws, size_t ws_size,
                              hipStream_t stream) {
  (void)in_sizes; (void)n_in; (void)out_size; (void)ws_size;
  const float* summ = (const float*)d_in[0];
  const float* dec  = (const float*)d_in[1];
  const float* Wh   = (const float*)d_in[2];
  const float* bh   = (const float*)d_in[3];
  const float* W1   = (const float*)d_in[4];
  const float* W2   = (const float*)d_in[5];
  const float* Wo   = (const float*)d_in[6];
  const float* bo   = (const float*)d_in[7];
  const float* gam  = (const float*)d_in[8];
  const float* bet  = (const float*)d_in[9];
  float* out = (float*)d_out;

  char* ws = (char*)d_ws;
  unsigned short* Mbuf  = (unsigned short*)(ws);                 // 32 MB bf16 M; later F
  unsigned short* Hbuf  = (unsigned short*)(ws + 33554432);      // 32 MB bf16 H
  float*          part  = (float*)(ws + 67108864);               // 2 MB fp32 partial sums
  float*          spo   = (float*)(ws + 69206016);               // 16 KB
  unsigned short* WhT   = (unsigned short*)(ws + 69238784);      // 512 KB bf16
  unsigned short* WoT   = (unsigned short*)(ws + 69763072);      // 512 KB bf16
  unsigned short* W2b   = (unsigned short*)(ws + 70287360);      // 512 KB bf16 (W2 row-major)
  unsigned short* W2WoT = (unsigned short*)(ws + 70811648);      // 512 KB bf16 (= (W2@Wo)^T)
  unsigned short* W1b   = (unsigned short*)(ws + 71335936);      // 512 KB bf16 (W1 row-major)
  unsigned short* W1WoT = (unsigned short*)(ws + 71860224);      // 512 KB bf16 (= (W1@Wo)^T)

  // weight prep (fp32 -> bf16)
  k_transpose512<<<64, 256, 0, stream>>>(Wh, WhT);
  k_transpose512<<<64, 256, 0, stream>>>(Wo, WoT);
  k_convert512<<<256, 256, 0, stream>>>(W2, W2b);
  k_convert512<<<256, 256, 0, stream>>>(W1, W1b);
  // (W2@Wo)^T = Wo^T @ W2^T : A = WoT, BT = W2b   (both row-major bf16)
  k_gemm<2><<<dim3(4, 4), 256, 0, stream>>>(WoT, W2b, W2WoT, nullptr, nullptr);
  // (W1@Wo)^T = Wo^T @ W1^T : A = WoT, BT = W1b
  k_gemm<2><<<dim3(4, 4), 256, 0, stream>>>(WoT, W1b, W1WoT, nullptr, nullptr);

  // causal running mean -> M (bf16)
  k_scan_partial<<<512, 256, 0, stream>>>(dec, part);
  k_scan_prefix<<<16, 256, 0, stream>>>(part);
  k_scan_apply<<<512, 256, 0, stream>>>(dec, part, Mbuf);

  // spo[b][n] = bo[n] + summ[b][:] . W1WoT[n][:]   (wave per output)
  k_svec<<<1024, 256, 0, stream>>>(summ, W1WoT, bo, spo);

  // H = tanh(M @ Wh + bh)
  k_gemm<0><<<dim3(256, 4), 256, 0, stream>>>(Mbuf, WhT, Hbuf, bh, nullptr);
  // F = tanh(spo[b] - H @ (W2@Wo))   (into Mbuf; M is dead)
  k_gemm<3><<<dim3(256, 4), 256, 0, stream>>>(Hbuf, W2WoT, Mbuf, nullptr, spo);

  // out = LayerNorm(F + dec) * gamma + beta
  k_ln<<<8192, 256, 0, stream>>>(Mbuf, dec, gam, bet, out);
}

// Round 4
// 265.402 us; speedup vs baseline: 1.3105x; 1.0421x over previous
//
#include <hip/hip_runtime.h>
#include <hip/hip_bf16.h>
#include <stdint.h>
#include <stddef.h>

#define DEV static __device__ __forceinline__

typedef __attribute__((ext_vector_type(8))) short short8;   // 8 bf16 (4 VGPRs) MFMA A/B frag
typedef __attribute__((ext_vector_type(4))) float floatx4;  // MFMA C/D frag

constexpr int Tn = 4096, Dn = 512;
constexpr int NC = 128, CTm = 32;   // scan: 128 chunks of 32 along T

union U8s { uint4 u4; unsigned short us[8]; };
union U4f { float4 f4; float f[4]; };
union U4s { uint2 u2; unsigned short us[4]; };

DEV float b2f(unsigned short u) {
  union { unsigned int i; float f; } c; c.i = ((unsigned int)u) << 16; return c.f;
}
DEV unsigned short f2b(float f) {  // RNE float->bf16
  union { float f; unsigned int u; } c; c.f = f;
  unsigned int r = c.u + 0x7fffu + ((c.u >> 16) & 1u);
  return (unsigned short)(r >> 16);
}
DEV float fast_tanh(float x) {     // robust at +/-inf: 1-2/(e^{2x}+1)
  float e = __expf(2.0f * x);
  return 1.0f - 2.0f / (e + 1.0f);
}

typedef __attribute__((address_space(1))) void GVOID;
typedef __attribute__((address_space(3))) void LVOID;
DEV void async16(const unsigned short* g, unsigned short* l) {
  __builtin_amdgcn_global_load_lds((GVOID*)g, (LVOID*)l, 16, 0, 0);
}

// ---------------- scan pass 1: per-chunk partial sums (fp32) ----------------
__global__ void k_scan_partial(const float* __restrict__ dec, float* __restrict__ part) {
  int idx = blockIdx.x * 256 + threadIdx.x;   // B*NC*(D/4) = 131072 threads
  int d4 = idx & 127;
  int c  = (idx >> 7) & (NC - 1);
  int b  = idx >> 14;
  const float* p = dec + ((size_t)b * Tn + (size_t)c * CTm) * Dn + d4 * 4;
  float s[4] = {0,0,0,0};
#pragma unroll 4
  for (int i = 0; i < CTm; ++i) {
    U4f v; v.f4 = *(const float4*)(p + (size_t)i * Dn);
#pragma unroll
    for (int j = 0; j < 4; ++j) s[j] += v.f[j];
  }
  float* o = part + ((size_t)(b * NC + c)) * Dn + d4 * 4;
#pragma unroll
  for (int j = 0; j < 4; ++j) o[j] = s[j];
}

// -------- scan pass 2: local chunk-prefix + running mean -> bf16 M ----------
__global__ void k_scan_apply(const float* __restrict__ dec,
                             const float* __restrict__ part,
                             unsigned short* __restrict__ M) {
  int idx = blockIdx.x * 256 + threadIdx.x;   // B*NC*(D/8) = 65536 threads
  int d8 = idx & 63;
  int c  = (idx >> 6) & (NC - 1);
  int b  = idx >> 13;
  size_t rbase = (size_t)b * Tn + (size_t)c * CTm;
  float s[8] = {0,0,0,0,0,0,0,0};
  // exclusive prefix over preceding chunks (part is per-chunk sums, L2-resident)
  const float* pb = part + (size_t)b * NC * Dn + d8 * 8;
  for (int cc = 0; cc < c; ++cc) {
    U4f p0, p1;
    p0.f4 = *(const float4*)(pb + (size_t)cc * Dn);
    p1.f4 = *(const float4*)(pb + (size_t)cc * Dn + 4);
#pragma unroll
    for (int j = 0; j < 4; ++j) { s[j] += p0.f[j]; s[j + 4] += p1.f[j]; }
  }
  int t0 = c * CTm;
  for (int i = 0; i < CTm; ++i) {
    U4f v0, v1; U8s o;
    v0.f4 = *(const float4*)(dec + (rbase + i) * Dn + d8 * 8);
    v1.f4 = *(const float4*)(dec + (rbase + i) * Dn + d8 * 8 + 4);
    float inv = 1.0f / (float)(t0 + i + 1);
#pragma unroll
    for (int j = 0; j < 4; ++j) {
      s[j] += v0.f[j];     o.us[j]     = f2b(s[j] * inv);
      s[j + 4] += v1.f[j]; o.us[j + 4] = f2b(s[j + 4] * inv);
    }
    *(uint4*)(M + (rbase + i) * Dn + d8 * 8) = o.u4;
  }
}

// ------- spo[b][n] = bo[n] + sum_j summ[b][j] * W1WoT[n][j]  (wave/output) --
__global__ void k_svec(const float* __restrict__ summ,
                       const unsigned short* __restrict__ W1WoT,
                       const float* __restrict__ bo,
                       float* __restrict__ spo) {
  int widx = blockIdx.x * 4 + (threadIdx.x >> 6);   // 4096 waves total
  int lane = threadIdx.x & 63;
  int n = widx & 511; int b = widx >> 9;
  U8s w8; w8.u4 = *(const uint4*)(W1WoT + (size_t)n * Dn + lane * 8);
  U4f s0, s1;
  s0.f4 = *(const float4*)(summ + (size_t)b * Dn + lane * 8);
  s1.f4 = *(const float4*)(summ + (size_t)b * Dn + lane * 8 + 4);
  float acc = 0.f;
#pragma unroll
  for (int j = 0; j < 4; ++j) acc += s0.f[j] * b2f(w8.us[j]);
#pragma unroll
  for (int j = 0; j < 4; ++j) acc += s1.f[j] * b2f(w8.us[j + 4]);
#pragma unroll
  for (int o = 32; o > 0; o >>= 1) acc += __shfl_xor(acc, o, 64);
  if (lane == 0) spo[(size_t)b * Dn + n] = acc + bo[n];
}

// ---- weight prep, one dispatch: WhT, WoT (transpose), W1b, W2b (convert) ---
// grid 192: [0,64) Wh->WhT ; [64,128) Wo->WoT ; [128,160) W1->W1b ; [160,192) W2->W2b
__global__ void k_wprep(const float* __restrict__ Wh, const float* __restrict__ Wo,
                        const float* __restrict__ W1, const float* __restrict__ W2,
                        unsigned short* __restrict__ WhT, unsigned short* __restrict__ WoT,
                        unsigned short* __restrict__ W1b, unsigned short* __restrict__ W2b) {
  int blk = blockIdx.x;
  if (blk < 128) {          // transpose section
    const float* in = (blk < 64) ? Wh : Wo;
    unsigned short* out = (blk < 64) ? WhT : WoT;
    int lb = blk & 63;
    __shared__ float t[64][65];
    int n0 = (lb & 7) * 64, k0 = (lb >> 3) * 64;
#pragma unroll
    for (int l = 0; l < 16; ++l) {
      int lin = l * 256 + threadIdx.x;
      int r = lin >> 6, c = lin & 63;
      t[r][c] = in[(size_t)(k0 + r) * 512 + n0 + c];
    }
    __syncthreads();
#pragma unroll
    for (int l = 0; l < 16; ++l) {
      int lin = l * 256 + threadIdx.x;
      int r = lin >> 6, c = lin & 63;
      out[(size_t)(n0 + r) * 512 + k0 + c] = f2b(t[c][r]);
    }
  } else {                  // convert section: 32 blocks x 256 thr x 32 elems = 262144
    const float* in = (blk < 160) ? W1 : W2;
    unsigned short* out = (blk < 160) ? W1b : W2b;
    int lb = (blk - 128) & 31;
    size_t base = ((size_t)lb * 256 + threadIdx.x) * 32;
#pragma unroll
    for (int l = 0; l < 8; ++l) {
      U4f v; v.f4 = *(const float4*)(in + base + l * 4);
      U4s o;
#pragma unroll
      for (int j = 0; j < 4; ++j) o.us[j] = f2b(v.f[j]);
      *(uint2*)(out + base + l * 4) = o.u2;
    }
  }
}

// ---------------- MFMA GEMM core: C[m][n] = epi(sum_k A[m][k]*BT[n][k]) -----
// A, BT, C: bf16. EPI 0: tanh(acc + bias[n]) ; EPI 2: acc ;
// EPI 3: tanh(sproj[b][n] - acc)  (b = rowg >> 12)
template<int EPI>
DEV void gemm_core(const unsigned short* __restrict__ A, const unsigned short* __restrict__ BT,
                   unsigned short* __restrict__ C, const float* __restrict__ bias,
                   const float* __restrict__ sproj, int m0, int n0) {
  __shared__ alignas(16) unsigned short sA[128 * 64];
  __shared__ alignas(16) unsigned short sB[128 * 64];
  const int tid  = threadIdx.x;
  const int lane = tid & 63;
  const int w    = tid >> 6;
  const int wm   = (w >> 1) * 64;
  const int wn   = (w & 1) * 64;
  const int rs   = lane & 15;
  const int quad = lane >> 4;

  floatx4 acc[4][4];
#pragma unroll
  for (int i = 0; i < 4; ++i)
#pragma unroll
    for (int j = 0; j < 4; ++j) acc[i][j] = (floatx4){0.f, 0.f, 0.f, 0.f};

  for (int kt = 0; kt < 512; kt += 64) {
    // stage A[128x64], BT[128x64] -> LDS via width-16 global_load_lds
#pragma unroll
    for (int l = 0; l < 4; ++l) {
      int ch = l * 256 + tid;
      int r = ch >> 3, kc = ch & 7;
      async16(A  + (size_t)(m0 + r) * 512 + kt + kc * 8, sA + (size_t)ch * 8);
      async16(BT + (size_t)(n0 + r) * 512 + kt + kc * 8, sB + (size_t)ch * 8);
    }
    asm volatile("s_waitcnt vmcnt(0)" ::: "memory");
    __syncthreads();

#pragma unroll
    for (int kk = 0; kk < 2; ++kk) {
      const int kb = kk * 32 + quad * 8;   // A-frag layout: A[m=rs][k=quad*8+j]
      short8 af[4], bfr[4];
#pragma unroll
      for (int i = 0; i < 4; ++i)
        af[i] = *(const short8*)(sA + (size_t)(wm + i * 16 + rs) * 64 + kb);
#pragma unroll
      for (int j = 0; j < 4; ++j)
        bfr[j] = *(const short8*)(sB + (size_t)(wn + j * 16 + rs) * 64 + kb);
#pragma unroll
      for (int i = 0; i < 4; ++i)
#pragma unroll
        for (int j = 0; j < 4; ++j)
          acc[i][j] = __builtin_amdgcn_mfma_f32_16x16x32_bf16(af[i], bfr[j], acc[i][j], 0, 0, 0);
    }
    __syncthreads();
  }

  // C/D layout: col = lane&15, row = quad*4 + reg
#pragma unroll
  for (int i = 0; i < 4; ++i) {
#pragma unroll
    for (int j = 0; j < 4; ++j) {
      const int colg = n0 + wn + j * 16 + rs;
#pragma unroll
      for (int r = 0; r < 4; ++r) {
        const int rowg = m0 + wm + i * 16 + quad * 4 + r;
        float v = acc[i][j][r];
        if constexpr (EPI == 0)      v = fast_tanh(v + bias[colg]);
        else if constexpr (EPI == 3) v = fast_tanh(sproj[(rowg >> 12) * Dn + colg] - v);
        C[(size_t)rowg * 512 + colg] = f2b(v);
      }
    }
  }
}

template<int EPI>
__global__ __launch_bounds__(256, 2)
void k_gemm(const unsigned short* __restrict__ A, const unsigned short* __restrict__ BT,
            unsigned short* __restrict__ C, const float* __restrict__ bias,
            const float* __restrict__ sproj) {
  gemm_core<EPI>(A, BT, C, bias, sproj, blockIdx.x * 128, blockIdx.y * 128);
}

// Both weight GEMMs in one dispatch: z=0 -> W2WoT, z=1 -> W1WoT  (A = WoT)
__global__ __launch_bounds__(256, 2)
void k_wgemm(const unsigned short* __restrict__ WoT,
             const unsigned short* __restrict__ W2b, const unsigned short* __restrict__ W1b,
             unsigned short* __restrict__ W2WoT, unsigned short* __restrict__ W1WoT) {
  const unsigned short* BT = blockIdx.z ? W1b : W2b;
  unsigned short* C = blockIdx.z ? W1WoT : W2WoT;
  gemm_core<2>(WoT, BT, C, nullptr, nullptr, blockIdx.x * 128, blockIdx.y * 128);
}

// ---------------- residual + LayerNorm (wave per row), fp32 out -------------
__global__ void k_ln(const unsigned short* __restrict__ F, const float* __restrict__ dec,
                     const float* __restrict__ gamma, const float* __restrict__ beta,
                     float* __restrict__ out) {
  int row  = blockIdx.x * 4 + (threadIdx.x >> 6);
  int lane = threadIdx.x & 63;
  size_t base = (size_t)row * Dn + lane * 8;
  U8s f8; f8.u4 = *(const uint4*)(F + base);
  U4f d0, d1; d0.f4 = *(const float4*)(dec + base); d1.f4 = *(const float4*)(dec + base + 4);
  float x[8]; float s = 0.f, sq = 0.f;
#pragma unroll
  for (int j = 0; j < 8; ++j) {
    float dv = (j < 4) ? d0.f[j] : d1.f[j - 4];
    x[j] = b2f(f8.us[j]) + dv; s += x[j]; sq += x[j] * x[j];
  }
#pragma unroll
  for (int o = 32; o > 0; o >>= 1) { s += __shfl_xor(s, o, 64); sq += __shfl_xor(sq, o, 64); }
  float mu   = s * (1.0f / 512.0f);
  float var  = sq * (1.0f / 512.0f) - mu * mu;
  float rstd = rsqrtf(var + 1e-6f);
  U4f g0, g1, b0, b1, o0, o1;
  g0.f4 = *(const float4*)(gamma + lane * 8); g1.f4 = *(const float4*)(gamma + lane * 8 + 4);
  b0.f4 = *(const float4*)(beta  + lane * 8); b1.f4 = *(const float4*)(beta  + lane * 8 + 4);
#pragma unroll
  for (int j = 0; j < 8; ++j) {
    float g = (j < 4) ? g0.f[j] : g1.f[j - 4];
    float b = (j < 4) ? b0.f[j] : b1.f[j - 4];
    float v = (x[j] - mu) * rstd * g + b;
    if (j < 4) o0.f[j] = v; else o1.f[j - 4] = v;
  }
  *(float4*)(out + base) = o0.f4;
  *(float4*)(out + base + 4) = o1.f4;
}

extern "C" void kernel_launch(void* const* d_in, const int* in_sizes, int n_in,
                              void* d_out, int out_size, void* d_ws, size_t ws_size,
                              hipStream_t stream) {
  (void)in_sizes; (void)n_in; (void)out_size; (void)ws_size;
  const float* summ = (const float*)d_in[0];
  const float* dec  = (const float*)d_in[1];
  const float* Wh   = (const float*)d_in[2];
  const float* bh   = (const float*)d_in[3];
  const float* W1   = (const float*)d_in[4];
  const float* W2   = (const float*)d_in[5];
  const float* Wo   = (const float*)d_in[6];
  const float* bo   = (const float*)d_in[7];
  const float* gam  = (const float*)d_in[8];
  const float* bet  = (const float*)d_in[9];
  float* out = (float*)d_out;

  char* ws = (char*)d_ws;
  unsigned short* Mbuf  = (unsigned short*)(ws);                 // 32 MB bf16 M; later F
  unsigned short* Hbuf  = (unsigned short*)(ws + 33554432);      // 32 MB bf16 H
  float*          part  = (float*)(ws + 67108864);               // 2 MB fp32 chunk sums
  float*          spo   = (float*)(ws + 69206016);               // 16 KB
  unsigned short* WhT   = (unsigned short*)(ws + 69238784);      // 512 KB bf16
  unsigned short* WoT   = (unsigned short*)(ws + 69763072);      // 512 KB bf16
  unsigned short* W2b   = (unsigned short*)(ws + 70287360);      // 512 KB bf16 (W2 row-major)
  unsigned short* W2WoT = (unsigned short*)(ws + 70811648);      // 512 KB bf16 (= (W2@Wo)^T)
  unsigned short* W1b   = (unsigned short*)(ws + 71335936);      // 512 KB bf16 (W1 row-major)
  unsigned short* W1WoT = (unsigned short*)(ws + 71860224);      // 512 KB bf16 (= (W1@Wo)^T)

  // chunk sums for the scan (independent of weight prep)
  k_scan_partial<<<512, 256, 0, stream>>>(dec, part);

  // weight prep: transposes + converts in one dispatch, then both weight GEMMs
  k_wprep<<<192, 256, 0, stream>>>(Wh, Wo, W1, W2, WhT, WoT, W1b, W2b);
  k_wgemm<<<dim3(4, 4, 2), 256, 0, stream>>>(WoT, W2b, W1b, W2WoT, W1WoT);

  // spo[b][n] = bo[n] + summ[b][:] . W1WoT[n][:]   (wave per output)
  k_svec<<<1024, 256, 0, stream>>>(summ, W1WoT, bo, spo);

  // causal running mean -> M (bf16); local chunk-prefix fused in
  k_scan_apply<<<256, 256, 0, stream>>>(dec, part, Mbuf);

  // H = tanh(M @ Wh + bh)
  k_gemm<0><<<dim3(256, 4), 256, 0, stream>>>(Mbuf, WhT, Hbuf, bh, nullptr);
  // F = tanh(spo[b] - H @ (W2@Wo))   (into Mbuf; M is dead)
  k_gemm<3><<<dim3(256, 4), 256, 0, stream>>>(Hbuf, W2WoT, Mbuf, nullptr, spo);

  // out = LayerNorm(F + dec) * gamma + beta
  k_ln<<<8192, 256, 0, stream>>>(Mbuf, dec, gam, bet, out);
}